// Round 7
// baseline (1096.823 us; speedup 1.0000x reference)
//
#include <hip/hip_runtime.h>
#include <math.h>

#define NB 1000      // graphs
#define NN 100       // nodes per graph
#define NNP 112      // padded rows (16 row-groups * 7)
#define EPG 1000     // edges per graph
#define FIN 14
#define HD 128
#define KP1 80
#define KP2 64
#define NT 512       // threads per block

// LDS float offsets
#define O_HS   0                        // [112][128] = 14336
#define O_CB   14336                    // [112][32] = 3584 (alias xg[0:1600], ag[1600:3200]; pads 3200:3584)
#define O_SS   17920                    // 1000 ints: CSR sorted sources
#define O_RP   18920                    // 104 ints: rowptr
#define O_SC   19024                    // 100
#define O_MK1  19124                    // 100
#define O_MK2  19224                    // 100
#define O_P1   19324                    // 128
#define O_P2   19452                    // 128
#define O_ZSH  19580                    // 256
#define O_ZRD  19836                    // 512 floats (ints deg[0:128], pos[128:228] during CSR build)
#define O_INV  20348                    // 2
#define NSM    20350
#define SMEM_BYTES (NSM * 4)            // 81400 B -> 2 blocks/CU (160 KB pool)

// Occupancy model (r5/r6 evidence): effective regs ~ 2x reported VGPR
// (unified VGPR/AGPR). VGPR=64 -> 4 waves/SIMD (16/CU, matches r5's 43%);
// VGPR=120 -> 2 waves/SIMD (8/CU, matches r6's 22.7%). LDS 81.4KB caps at
// 2 blocks = 16 waves/CU. Target: VGPR<=64 AND zero spill (r5 spilled
// 280B/thread = 220MB HBM = its whole 300us). Live set cut via w[4].
__global__ __launch_bounds__(NT, 4) void fused_gnn(
    const float* __restrict__ x, const int* __restrict__ ei,
    const float* __restrict__ Wrel1, const float* __restrict__ Wroot1,
    const float* __restrict__ b1, const float* __restrict__ p1,
    const float* __restrict__ Wrel2, const float* __restrict__ Wroot2,
    const float* __restrict__ b2, const float* __restrict__ p2,
    const float* __restrict__ l1w, const float* __restrict__ l1b,
    const float* __restrict__ l2w, const float* __restrict__ l2b,
    const float* __restrict__ l3w, const float* __restrict__ l3b,
    float* __restrict__ out)
{
    extern __shared__ float smf[];
    float* Hs  = smf + O_HS;
    float* CB  = smf + O_CB;
    float* xg  = CB;                 // [100][16] (cols 14,15 zero)
    float* ag  = CB + 1600;          // [100][16]
    int*   ssrc = (int*)(smf + O_SS);
    int*   rowptr = (int*)(smf + O_RP);
    float* sc  = smf + O_SC;
    float* mk1 = smf + O_MK1;
    float* mk2 = smf + O_MK2;
    float* p1s = smf + O_P1;
    float* p2s = smf + O_P2;
    float* zsh = smf + O_ZSH;
    float* zrd = smf + O_ZRD;
    int*   zdi = (int*)(smf + O_ZRD);   // deg[0:128] / pos[128:228] during build
    float* inv = smf + O_INV;

    const int tid = threadIdx.x;
    const int g = blockIdx.x;
    const int bn = g * NN;
    const int* srcp = ei + g * EPG;
    const int* dstp = ei + NB * EPG + g * EPG;

    // ---------- P0a: stage xg/ag, zero pads, p vectors + norms, zero deg ----------
    for (int t = tid; t < 1600; t += NT) {
        int i = t >> 4, f = t & 15;
        xg[t] = (f < FIN) ? x[bn * FIN + i * FIN + f] : 0.f;
        ag[t] = 0.f;
    }
    if (tid < 384) CB[3200 + tid] = 0.f;              // CB pad rows 100..111
    for (int t = tid; t < (NNP - NN) * HD; t += NT) Hs[NN * HD + t] = 0.f;
    if (tid < 128) { p1s[tid] = p1[tid]; p2s[tid] = p2[tid]; zdi[tid] = 0; }
    if (tid >= 256 && tid < 320) {
        int l = tid - 256;
        float a = p1[l], b = p1[l + 64];
        float v = a * a + b * b;
        for (int s = 1; s < 64; s <<= 1) v += __shfl_xor(v, s);
        if (l == 0) inv[0] = rsqrtf(v);
    } else if (tid >= 320 && tid < 384) {
        int l = tid - 320;
        float a = p2[l], b = p2[l + 64];
        float v = a * a + b * b;
        for (int s = 1; s < 64; s <<= 1) v += __shfl_xor(v, s);
        if (l == 0) inv[1] = rsqrtf(v);
    }
    __syncthreads();

    // ---------- P0b: CSR build — count ----------
    for (int e = tid; e < EPG; e += NT) {
        int dl = dstp[e] - bn;
        atomicAdd(&zdi[dl], 1);
    }
    __syncthreads();
    // ---------- P0c: exclusive scan via wave shfl (deg[0:128] -> rowptr) ----------
    if (tid < 64) {
        int a = zdi[tid], b = zdi[tid + 64];
        for (int off = 1; off < 64; off <<= 1) { int t = __shfl_up(a, off); if (tid >= off) a += t; }
        int totA = __shfl(a, 63);
        for (int off = 1; off < 64; off <<= 1) { int t = __shfl_up(b, off); if (tid >= off) b += t; }
        b += totA;
        rowptr[tid + 1] = a;          // inclusive -> rowptr[i+1]
        if (tid + 65 <= 103) rowptr[tid + 65] = b;
        if (tid == 0) rowptr[0] = 0;
    }
    __syncthreads();
    if (tid < NN) zdi[128 + tid] = rowptr[tid];       // pos cursors
    __syncthreads();
    // ---------- P0d: CSR scatter ----------
    for (int e = tid; e < EPG; e += NT) {
        int sl = srcp[e] - bn;
        int dl = dstp[e] - bn;
        int slot = atomicAdd(&zdi[128 + dl], 1);
        ssrc[slot] = sl;
    }
    __syncthreads();

    // ---------- P1: conv1 agg via CSR: ag[i][f] = sum_in-edges xg[src][f] ----------
    {
        const int f = tid & 15;
        if (f < FIN) {
            for (int i = tid >> 4; i < NN; i += 32) {
                int s0 = rowptr[i], s1 = rowptr[i + 1];
                float s = 0.f;
                for (int sl0 = s0; sl0 < s1; ++sl0)
                    s += xg[ssrc[sl0] * 16 + f];
                ag[i * 16 + f] = s;
            }
        }
    }
    __syncthreads();

    // ---------- P2: h1 = relu(ag@Wrel1 + xg@Wroot1 + b1), float4 LDS reads ----------
    {
        const int j = tid & 127;
        float wr[16], wo[16];
#pragma unroll
        for (int k = 0; k < FIN; ++k) { wr[k] = Wrel1[k * HD + j]; wo[k] = Wroot1[k * HD + j]; }
        wr[14] = wr[15] = wo[14] = wo[15] = 0.f;      // pad cols of ag/xg are zero too
        const float bb = b1[j];
        for (int i = tid >> 7; i < NN; i += 4) {
            const float4* agv = (const float4*)&ag[i * 16];
            const float4* xgv = (const float4*)&xg[i * 16];
            float s = bb;
#pragma unroll
            for (int q = 0; q < 4; ++q) {
                float4 a = agv[q], xx = xgv[q];
                s += a.x * wr[4 * q] + a.y * wr[4 * q + 1] + a.z * wr[4 * q + 2] + a.w * wr[4 * q + 3]
                   + xx.x * wo[4 * q] + xx.y * wo[4 * q + 1] + xx.z * wo[4 * q + 2] + xx.w * wo[4 * q + 3];
            }
            Hs[i * HD + j] = fmaxf(s, 0.f);
        }
    }
    __syncthreads();

    // ---------- P3: pool1 score (4 lanes/row, skewed) + top-80 + scale + readout1 ----------
    if (tid < 400) {
        const int row = tid >> 2, q = tid & 3;
        float d = 0.f;
        for (int kk = 0; kk < 32; ++kk) {
            int k = q * 32 + ((kk + tid) & 31);
            d += Hs[row * HD + k] * p1s[k];
        }
        d += __shfl_xor(d, 1);
        d += __shfl_xor(d, 2);
        if (q == 0) sc[row] = tanhf(d * inv[0]);
    }
    __syncthreads();
    if (tid < 400) {                    // rank-count, 4 lanes/row
        const int row = tid >> 2, q = tid & 3;
        float si = sc[row]; int cnt = 0;
        for (int j2 = q * 25; j2 < q * 25 + 25; ++j2) cnt += (sc[j2] > si) ? 1 : 0;
        cnt += __shfl_xor(cnt, 1);
        cnt += __shfl_xor(cnt, 2);
        if (q == 0) mk1[row] = (cnt < KP1) ? 1.f : 0.f;
    }
    __syncthreads();
    for (int o = tid; o < NN * HD; o += NT) { int i = o >> 7; Hs[o] *= sc[i] * mk1[i]; }
    __syncthreads();
    {
        const int col = tid & 127, ch = tid >> 7;
        float mean = 0.f, mx = -1e30f;
        for (int i = ch * 25; i < ch * 25 + 25; ++i) {
            float v = Hs[i * HD + col];
            mean += v;
            if (mk1[i] > 0.f && v > mx) mx = v;
        }
        zrd[tid] = mean; CB[tid] = mx;
    }
    __syncthreads();
    if (tid < HD) {
        float mean = zrd[tid] + zrd[128 + tid] + zrd[256 + tid] + zrd[384 + tid];
        float mx = fmaxf(fmaxf(CB[tid], CB[128 + tid]), fmaxf(CB[256 + tid], CB[384 + tid]));
        zsh[tid] = mean * (1.f / KP1);
        zsh[HD + tid] = mx;
    }

    // ---------- P4: conv2: acc = b2 + Hs@Wroot2 + sum_c CSRagg@Wrel2 ----------
    const int tr = tid >> 5, tc = tid & 31;     // 16 row-groups x 32 col-groups
    const int i0 = tr * 7, j0 = tc * 4;
    const float4* Wrel2v  = (const float4*)Wrel2;
    const float4* Wroot2v = (const float4*)Wroot2;

    float acc[7][4];
    {
        float4 bv = ((const float4*)b2)[tc];
#pragma unroll
        for (int r = 0; r < 7; ++r) { acc[r][0] = bv.x; acc[r][1] = bv.y; acc[r][2] = bv.z; acc[r][3] = bv.w; }
    }
    // root pass: w[4]-batched weight loads (live set fits 64 VGPR), b128 LDS reads
    for (int k0 = 0; k0 < HD; k0 += 4) {
        float4 w[4];
#pragma unroll
        for (int u = 0; u < 4; ++u) w[u] = Wroot2v[(k0 + u) * 32 + tc];
#pragma unroll
        for (int r = 0; r < 7; ++r) {
            float4 a0 = *(const float4*)&Hs[(i0 + r) * HD + k0];
            acc[r][0] += a0.x * w[0].x + a0.y * w[1].x + a0.z * w[2].x + a0.w * w[3].x;
            acc[r][1] += a0.x * w[0].y + a0.y * w[1].y + a0.z * w[2].y + a0.w * w[3].y;
            acc[r][2] += a0.x * w[0].z + a0.y * w[1].z + a0.z * w[2].z + a0.w * w[3].z;
            acc[r][3] += a0.x * w[0].w + a0.y * w[1].w + a0.z * w[2].w + a0.w * w[3].w;
        }
    }
    // rel pass: 4 chunks of 32 cols; CSR gather (no atomics) then w[4] FMA
    for (int c = 0; c < 4; ++c) {
        __syncthreads();                     // prior CB readers done
        {
            const int jj = tid & 31;
            const int cb = c * 32 + jj;
            for (int i = tid >> 5; i < NN; i += 16) {
                int s0 = rowptr[i], s1 = rowptr[i + 1];
                float s = 0.f;
                for (int sl0 = s0; sl0 < s1; ++sl0)
                    s += Hs[ssrc[sl0] * HD + cb];
                CB[i * 32 + jj] = s;
            }
        }
        __syncthreads();
        for (int kk0 = 0; kk0 < 32; kk0 += 4) {
            float4 w[4];
#pragma unroll
            for (int u = 0; u < 4; ++u) w[u] = Wrel2v[(c * 32 + kk0 + u) * 32 + tc];
#pragma unroll
            for (int r = 0; r < 7; ++r) {
                float4 a0 = *(const float4*)&CB[(i0 + r) * 32 + kk0];
                acc[r][0] += a0.x * w[0].x + a0.y * w[1].x + a0.z * w[2].x + a0.w * w[3].x;
                acc[r][1] += a0.x * w[0].y + a0.y * w[1].y + a0.z * w[2].y + a0.w * w[3].y;
                acc[r][2] += a0.x * w[0].z + a0.y * w[1].z + a0.z * w[2].z + a0.w * w[3].z;
                acc[r][3] += a0.x * w[0].w + a0.y * w[1].w + a0.z * w[2].w + a0.w * w[3].w;
            }
        }
    }
    __syncthreads();                          // all readers of Hs done
#pragma unroll
    for (int r = 0; r < 7; ++r) {
        float4 v;
        v.x = fmaxf(acc[r][0], 0.f); v.y = fmaxf(acc[r][1], 0.f);
        v.z = fmaxf(acc[r][2], 0.f); v.w = fmaxf(acc[r][3], 0.f);
        *(float4*)&Hs[(i0 + r) * HD + j0] = v;
    }
    __syncthreads();

    // ---------- P5: pool2 + readout2 ----------
    if (tid < 400) {
        const int row = tid >> 2, q = tid & 3;
        float d = 0.f;
        for (int kk = 0; kk < 32; ++kk) {
            int k = q * 32 + ((kk + tid) & 31);
            d += Hs[row * HD + k] * p2s[k];
        }
        d += __shfl_xor(d, 1);
        d += __shfl_xor(d, 2);
        if (q == 0) sc[row] = (mk1[row] > 0.f) ? tanhf(d * inv[1]) : -1e30f;
    }
    __syncthreads();
    if (tid < 400) {                    // rank-count, 4 lanes/row
        const int row = tid >> 2, q = tid & 3;
        float si = sc[row]; int cnt = 0;
        for (int j2 = q * 25; j2 < q * 25 + 25; ++j2) cnt += (sc[j2] > si) ? 1 : 0;
        cnt += __shfl_xor(cnt, 1);
        cnt += __shfl_xor(cnt, 2);
        if (q == 0) mk2[row] = (mk1[row] > 0.f && cnt < KP2) ? 1.f : 0.f;
    }
    __syncthreads();
    for (int o = tid; o < NN * HD; o += NT) { int i = o >> 7; Hs[o] *= sc[i] * mk2[i]; }
    __syncthreads();
    {
        const int col = tid & 127, ch = tid >> 7;
        float mean = 0.f, mx = -1e30f;
        for (int i = ch * 25; i < ch * 25 + 25; ++i) {
            float v = Hs[i * HD + col];
            mean += v;
            if (mk2[i] > 0.f && v > mx) mx = v;
        }
        zrd[tid] = mean; CB[tid] = mx;
    }
    __syncthreads();
    if (tid < HD) {
        float mean = zrd[tid] + zrd[128 + tid] + zrd[256 + tid] + zrd[384 + tid];
        float mx = fmaxf(fmaxf(CB[tid], CB[128 + tid]), fmaxf(CB[256 + tid], CB[384 + tid]));
        zsh[tid] += mean * (1.f / KP2);
        zsh[HD + tid] += mx;
    }
    __syncthreads();

    // ---------- P6: MLP + log_softmax (z1 -> CB[0:128], z2 -> CB[256:288]) ----------
    {   // l1: 256 -> 128, k split over 4 chunks of 64
        const int j = tid & 127, q = tid >> 7;
        float a = 0.f;
        for (int kk = 0; kk < 64; ++kk) {
            int k = q * 64 + kk;
            a += zsh[k] * l1w[k * HD + j];
        }
        zrd[tid] = a;
    }
    __syncthreads();
    if (tid < HD)
        CB[tid] = fmaxf(zrd[tid] + zrd[128 + tid] + zrd[256 + tid] + zrd[384 + tid] + l1b[tid], 0.f);
    __syncthreads();
    if (tid < 256) {   // l2: 128 -> 32, k split over 8 chunks of 16
        const int o = tid & 31, q = tid >> 5;
        float a = 0.f;
        for (int kk = 0; kk < 16; ++kk) {
            int k = q * 16 + kk;
            a += CB[k] * l2w[k * 32 + o];
        }
        zrd[tid] = a;
    }
    __syncthreads();
    if (tid < 32) {
        float v = l2b[tid];
#pragma unroll
        for (int q = 0; q < 8; ++q) v += zrd[q * 32 + tid];
        CB[256 + tid] = fmaxf(v, 0.f);
    }
    __syncthreads();
    if (tid == 0) {
        float o0 = l3b[0], o1 = l3b[1];
        for (int k = 0; k < 32; ++k) {
            float v = CB[256 + k];
            o0 += v * l3w[2 * k];
            o1 += v * l3w[2 * k + 1];
        }
        float m = fmaxf(o0, o1);
        float l = m + logf(expf(o0 - m) + expf(o1 - m));
        out[g * 2 + 0] = o0 - l;
        out[g * 2 + 1] = o1 - l;
    }
}

extern "C" void kernel_launch(void* const* d_in, const int* in_sizes, int n_in,
                              void* d_out, int out_size, void* d_ws, size_t ws_size,
                              hipStream_t stream)
{
    const float* x      = (const float*)d_in[0];
    const int*   ei     = (const int*)d_in[1];
    const float* Wrel1  = (const float*)d_in[2];
    const float* Wroot1 = (const float*)d_in[3];
    const float* b1     = (const float*)d_in[4];
    const float* p1     = (const float*)d_in[5];
    const float* Wrel2  = (const float*)d_in[6];
    const float* Wroot2 = (const float*)d_in[7];
    const float* b2     = (const float*)d_in[8];
    const float* p2     = (const float*)d_in[9];
    const float* l1w    = (const float*)d_in[10];
    const float* l1b    = (const float*)d_in[11];
    const float* l2w    = (const float*)d_in[12];
    const float* l2b    = (const float*)d_in[13];
    const float* l3w    = (const float*)d_in[14];
    const float* l3b    = (const float*)d_in[15];
    float* out = (float*)d_out;

    (void)hipFuncSetAttribute((const void*)fused_gnn,
                              hipFuncAttributeMaxDynamicSharedMemorySize, SMEM_BYTES);

    fused_gnn<<<dim3(NB), dim3(NT), SMEM_BYTES, stream>>>(
        x, ei, Wrel1, Wroot1, b1, p1, Wrel2, Wroot2, b2, p2,
        l1w, l1b, l2w, l2b, l3w, l3b, out);
}

// Round 8
// 888.701 us; speedup vs baseline: 1.2342x; 1.2342x over previous
//
#include <hip/hip_runtime.h>
#include <math.h>

#define NB 1000      // graphs
#define NN 100       // nodes per graph
#define EPG 1000     // edges per graph
#define FIN 14
#define HD 128
#define KP1 80
#define KP2 64
#define NT 512       // threads per block

// LDS float offsets
#define O_HS   0                        // [100][128] = 12800
#define O_CB   12800                    // 3200: conv1 {xg[100][16], ag[100][16]}; conv2 gather [80][32]; readout partials; MLP z1/z2
#define O_SS   16000                    // 1000 ints: CSR sorted sources
#define O_RP   17000                    // 104 ints: rowptr
#define O_SC   17104                    // 100
#define O_MK1  17204                    // 100
#define O_MK2  17304                    // 100 (80 used)
#define O_P1   17404                    // 128
#define O_P2   17532                    // 128
#define O_ZSH  17660                    // 256
#define O_ZRD  17916                    // 512 floats (ints deg[0:128], pos[128:228] during CSR build)
#define O_INV  18428                    // 2
#define O_AL   18430                    // 80 ints: compact alive row list
#define NSM    18510
#define SMEM_BYTES (NSM * 4)            // 74040 B -> 2 blocks/CU

// Empirical law (r5/r6/r7): launch_bounds (512,4) caps VGPR at 64; VGPR=64
// -> 2 blocks/CU (46% occ), VGPR=120 -> 1 block (22.7%). Must fit 64 with
// ZERO spill (r5: 28-acc tile spilled 143MB; r7: 2.1GB). Fix: compact conv2
// to the 80 alive rows -> 5x4 tile (20 acc) + w[4] -> live ~50 regs.
__global__ __launch_bounds__(NT, 4) void fused_gnn(
    const float* __restrict__ x, const int* __restrict__ ei,
    const float* __restrict__ Wrel1, const float* __restrict__ Wroot1,
    const float* __restrict__ b1, const float* __restrict__ p1,
    const float* __restrict__ Wrel2, const float* __restrict__ Wroot2,
    const float* __restrict__ b2, const float* __restrict__ p2,
    const float* __restrict__ l1w, const float* __restrict__ l1b,
    const float* __restrict__ l2w, const float* __restrict__ l2b,
    const float* __restrict__ l3w, const float* __restrict__ l3b,
    float* __restrict__ out)
{
    extern __shared__ float smf[];
    float* Hs  = smf + O_HS;
    float* CB  = smf + O_CB;
    float* xg  = CB;                 // [100][16] (cols 14,15 zero)
    float* ag  = CB + 1600;          // [100][16]
    int*   ssrc = (int*)(smf + O_SS);
    int*   rowptr = (int*)(smf + O_RP);
    float* sc  = smf + O_SC;
    float* mk1 = smf + O_MK1;
    float* mk2 = smf + O_MK2;
    float* p1s = smf + O_P1;
    float* p2s = smf + O_P2;
    float* zsh = smf + O_ZSH;
    float* zrd = smf + O_ZRD;
    int*   zdi = (int*)(smf + O_ZRD);   // deg[0:128] / pos[128:228] during build
    float* inv = smf + O_INV;
    int*   alive = (int*)(smf + O_AL);  // 80 compact alive rows (ascending)

    const int tid = threadIdx.x;
    const int g = blockIdx.x;
    const int bn = g * NN;
    const int* srcp = ei + g * EPG;
    const int* dstp = ei + NB * EPG + g * EPG;

    // ---------- P0a: stage xg, p vectors + norms, zero deg ----------
    for (int t = tid; t < 1600; t += NT) {
        int i = t >> 4, f = t & 15;
        xg[t] = (f < FIN) ? x[bn * FIN + i * FIN + f] : 0.f;
    }
    if (tid < 128) { p1s[tid] = p1[tid]; p2s[tid] = p2[tid]; zdi[tid] = 0; }
    if (tid >= 256 && tid < 320) {
        int l = tid - 256;
        float a = p1[l], b = p1[l + 64];
        float v = a * a + b * b;
        for (int s = 1; s < 64; s <<= 1) v += __shfl_xor(v, s);
        if (l == 0) inv[0] = rsqrtf(v);
    } else if (tid >= 320 && tid < 384) {
        int l = tid - 320;
        float a = p2[l], b = p2[l + 64];
        float v = a * a + b * b;
        for (int s = 1; s < 64; s <<= 1) v += __shfl_xor(v, s);
        if (l == 0) inv[1] = rsqrtf(v);
    }
    __syncthreads();

    // ---------- P0b: CSR build — count ----------
    for (int e = tid; e < EPG; e += NT) {
        int dl = dstp[e] - bn;
        atomicAdd(&zdi[dl], 1);
    }
    __syncthreads();
    // ---------- P0c: exclusive scan via wave shfl (deg[0:128] -> rowptr) ----------
    if (tid < 64) {
        int a = zdi[tid], b = zdi[tid + 64];
        for (int off = 1; off < 64; off <<= 1) { int t = __shfl_up(a, off); if (tid >= off) a += t; }
        int totA = __shfl(a, 63);
        for (int off = 1; off < 64; off <<= 1) { int t = __shfl_up(b, off); if (tid >= off) b += t; }
        b += totA;
        rowptr[tid + 1] = a;          // inclusive -> rowptr[i+1]
        if (tid + 65 <= 103) rowptr[tid + 65] = b;
        if (tid == 0) rowptr[0] = 0;
    }
    __syncthreads();
    if (tid < NN) zdi[128 + tid] = rowptr[tid];       // pos cursors
    __syncthreads();
    // ---------- P0d: CSR scatter ----------
    for (int e = tid; e < EPG; e += NT) {
        int sl = srcp[e] - bn;
        int dl = dstp[e] - bn;
        int slot = atomicAdd(&zdi[128 + dl], 1);
        ssrc[slot] = sl;
    }
    __syncthreads();

    // ---------- P1: conv1 agg via CSR: ag[i][f] = sum_in-edges xg[src][f] ----------
    {
        const int f = tid & 15;
        if (f < FIN) {
            for (int i = tid >> 4; i < NN; i += 32) {
                int s0 = rowptr[i], s1 = rowptr[i + 1];
                float s = 0.f;
                for (int sl0 = s0; sl0 < s1; ++sl0)
                    s += xg[ssrc[sl0] * 16 + f];
                ag[i * 16 + f] = s;
            }
        }
    }
    __syncthreads();

    // ---------- P2: h1 = relu(ag@Wrel1 + xg@Wroot1 + b1) (r5 form) ----------
    {
        const int j = tid & 127;
        float wr[FIN], wo[FIN];
#pragma unroll
        for (int k = 0; k < FIN; ++k) { wr[k] = Wrel1[k * HD + j]; wo[k] = Wroot1[k * HD + j]; }
        const float bb = b1[j];
        for (int i = tid >> 7; i < NN; i += 4) {
            float s = bb;
#pragma unroll
            for (int k = 0; k < FIN; ++k)
                s += ag[i * 16 + k] * wr[k] + xg[i * 16 + k] * wo[k];
            Hs[i * HD + j] = fmaxf(s, 0.f);
        }
    }
    __syncthreads();

    // ---------- P3: pool1 score + top-80 + compact list + scale + readout1 ----------
    if (tid < 400) {
        const int row = tid >> 2, q = tid & 3;
        float d = 0.f;
        for (int kk = 0; kk < 32; ++kk) {
            int k = q * 32 + ((kk + tid) & 31);
            d += Hs[row * HD + k] * p1s[k];
        }
        d += __shfl_xor(d, 1);
        d += __shfl_xor(d, 2);
        if (q == 0) sc[row] = tanhf(d * inv[0]);
    }
    __syncthreads();
    if (tid < 400) {                    // rank-count, 4 lanes/row
        const int row = tid >> 2, q = tid & 3;
        float si = sc[row]; int cnt = 0;
        for (int j2 = q * 25; j2 < q * 25 + 25; ++j2) cnt += (sc[j2] > si) ? 1 : 0;
        cnt += __shfl_xor(cnt, 1);
        cnt += __shfl_xor(cnt, 2);
        if (q == 0) mk1[row] = (cnt < KP1) ? 1.f : 0.f;
    }
    __syncthreads();
    // compact alive list (wave 0, deterministic ascending) || scale (all threads)
    if (tid < 64) {
        int a = (mk1[tid] > 0.f) ? 1 : 0;
        int b = (tid + 64 < NN && mk1[tid + 64] > 0.f) ? 1 : 0;
        int ia = a, ib = b;
        for (int off = 1; off < 64; off <<= 1) { int t = __shfl_up(ia, off); if (tid >= off) ia += t; }
        int totA = __shfl(ia, 63);
        for (int off = 1; off < 64; off <<= 1) { int t = __shfl_up(ib, off); if (tid >= off) ib += t; }
        int ea = ia - a, eb = totA + ib - b;
        if (a && ea < KP1) alive[ea] = tid;
        if (b && eb < KP1) alive[eb] = tid + 64;
    }
    for (int o = tid; o < NN * HD; o += NT) { int i = o >> 7; Hs[o] *= sc[i] * mk1[i]; }
    __syncthreads();
    {
        const int col = tid & 127, ch = tid >> 7;
        float mean = 0.f, mx = -1e30f;
        for (int i = ch * 25; i < ch * 25 + 25; ++i) {
            float v = Hs[i * HD + col];
            mean += v;
            if (mk1[i] > 0.f && v > mx) mx = v;
        }
        zrd[tid] = mean; CB[tid] = mx;
    }
    __syncthreads();
    if (tid < HD) {
        float mean = zrd[tid] + zrd[128 + tid] + zrd[256 + tid] + zrd[384 + tid];
        float mx = fmaxf(fmaxf(CB[tid], CB[128 + tid]), fmaxf(CB[256 + tid], CB[384 + tid]));
        zsh[tid] = mean * (1.f / KP1);
        zsh[HD + tid] = mx;
    }

    // ---------- P4: conv2 on 80 compact rows: acc = b2 + h1[alive]@Wroot2 + agg@Wrel2 ----------
    const int tr = tid >> 5, tc = tid & 31;     // 16 row-groups x 32 col-groups
    const int i0 = tr * 5, j0 = tc * 4;
    const float4* Wrel2v  = (const float4*)Wrel2;
    const float4* Wroot2v = (const float4*)Wroot2;

    int orow[5];
#pragma unroll
    for (int r = 0; r < 5; ++r) orow[r] = alive[i0 + r];

    float acc[5][4];
    {
        float4 bv = ((const float4*)b2)[tc];
#pragma unroll
        for (int r = 0; r < 5; ++r) { acc[r][0] = bv.x; acc[r][1] = bv.y; acc[r][2] = bv.z; acc[r][3] = bv.w; }
    }
    // root pass: w[4]-batched weight loads, b128 LDS reads (broadcast within 32-lane group)
    for (int k0 = 0; k0 < HD; k0 += 4) {
        float4 w[4];
#pragma unroll
        for (int u = 0; u < 4; ++u) w[u] = Wroot2v[(k0 + u) * 32 + tc];
#pragma unroll
        for (int r = 0; r < 5; ++r) {
            float4 a0 = *(const float4*)&Hs[orow[r] * HD + k0];
            acc[r][0] += a0.x * w[0].x + a0.y * w[1].x + a0.z * w[2].x + a0.w * w[3].x;
            acc[r][1] += a0.x * w[0].y + a0.y * w[1].y + a0.z * w[2].y + a0.w * w[3].y;
            acc[r][2] += a0.x * w[0].z + a0.y * w[1].z + a0.z * w[2].z + a0.w * w[3].z;
            acc[r][3] += a0.x * w[0].w + a0.y * w[1].w + a0.z * w[2].w + a0.w * w[3].w;
        }
    }
    // rel pass: 4 chunks of 32 input cols; CSR gather for alive rows only, then w[4] FMA
    for (int c = 0; c < 4; ++c) {
        __syncthreads();                     // prior CB readers done
        {
            const int jj = tid & 31;
            const int cb = c * 32 + jj;
            for (int r = tid >> 5; r < KP1; r += 16) {
                int i = alive[r];
                int s0 = rowptr[i], s1 = rowptr[i + 1];
                float s = 0.f;
                for (int sl0 = s0; sl0 < s1; ++sl0)
                    s += Hs[ssrc[sl0] * HD + cb];
                CB[r * 32 + jj] = s;
            }
        }
        __syncthreads();
        for (int kk0 = 0; kk0 < 32; kk0 += 4) {
            float4 w[4];
#pragma unroll
            for (int u = 0; u < 4; ++u) w[u] = Wrel2v[(c * 32 + kk0 + u) * 32 + tc];
#pragma unroll
            for (int r = 0; r < 5; ++r) {
                float4 a0 = *(const float4*)&CB[(i0 + r) * 32 + kk0];
                acc[r][0] += a0.x * w[0].x + a0.y * w[1].x + a0.z * w[2].x + a0.w * w[3].x;
                acc[r][1] += a0.x * w[0].y + a0.y * w[1].y + a0.z * w[2].y + a0.w * w[3].y;
                acc[r][2] += a0.x * w[0].z + a0.y * w[1].z + a0.z * w[2].z + a0.w * w[3].z;
                acc[r][3] += a0.x * w[0].w + a0.y * w[1].w + a0.z * w[2].w + a0.w * w[3].w;
            }
        }
    }
    __syncthreads();                          // all gather/root reads of Hs done
    // write h2 compact into Hs rows 0..79 (in place; all reads complete)
#pragma unroll
    for (int r = 0; r < 5; ++r) {
        float4 v;
        v.x = fmaxf(acc[r][0], 0.f); v.y = fmaxf(acc[r][1], 0.f);
        v.z = fmaxf(acc[r][2], 0.f); v.w = fmaxf(acc[r][3], 0.f);
        *(float4*)&Hs[(i0 + r) * HD + j0] = v;
    }
    __syncthreads();

    // ---------- P5: pool2 + readout2 on 80 compact rows ----------
    if (tid < 320) {
        const int row = tid >> 2, q = tid & 3;
        float d = 0.f;
        for (int kk = 0; kk < 32; ++kk) {
            int k = q * 32 + ((kk + tid) & 31);
            d += Hs[row * HD + k] * p2s[k];
        }
        d += __shfl_xor(d, 1);
        d += __shfl_xor(d, 2);
        if (q == 0) sc[row] = tanhf(d * inv[1]);
    }
    __syncthreads();
    if (tid < 320) {                    // rank-count among 80, 4 lanes/row
        const int row = tid >> 2, q = tid & 3;
        float si = sc[row]; int cnt = 0;
        for (int j2 = q * 20; j2 < q * 20 + 20; ++j2) cnt += (sc[j2] > si) ? 1 : 0;
        cnt += __shfl_xor(cnt, 1);
        cnt += __shfl_xor(cnt, 2);
        if (q == 0) mk2[row] = (cnt < KP2) ? 1.f : 0.f;
    }
    __syncthreads();
    for (int o = tid; o < KP1 * HD; o += NT) { int i = o >> 7; Hs[o] *= sc[i] * mk2[i]; }
    __syncthreads();
    {
        const int col = tid & 127, ch = tid >> 7;
        float mean = 0.f, mx = -1e30f;
        for (int i = ch * 20; i < ch * 20 + 20; ++i) {
            float v = Hs[i * HD + col];
            mean += v;
            if (mk2[i] > 0.f && v > mx) mx = v;
        }
        zrd[tid] = mean; CB[tid] = mx;
    }
    __syncthreads();
    if (tid < HD) {
        float mean = zrd[tid] + zrd[128 + tid] + zrd[256 + tid] + zrd[384 + tid];
        float mx = fmaxf(fmaxf(CB[tid], CB[128 + tid]), fmaxf(CB[256 + tid], CB[384 + tid]));
        zsh[tid] += mean * (1.f / KP2);
        zsh[HD + tid] += mx;
    }
    __syncthreads();

    // ---------- P6: MLP + log_softmax (z1 -> CB[0:128], z2 -> CB[256:288]) ----------
    {   // l1: 256 -> 128, k split over 4 chunks of 64
        const int j = tid & 127, q = tid >> 7;
        float a = 0.f;
        for (int kk = 0; kk < 64; ++kk) {
            int k = q * 64 + kk;
            a += zsh[k] * l1w[k * HD + j];
        }
        zrd[tid] = a;
    }
    __syncthreads();
    if (tid < HD)
        CB[tid] = fmaxf(zrd[tid] + zrd[128 + tid] + zrd[256 + tid] + zrd[384 + tid] + l1b[tid], 0.f);
    __syncthreads();
    if (tid < 256) {   // l2: 128 -> 32, k split over 8 chunks of 16
        const int o = tid & 31, q = tid >> 5;
        float a = 0.f;
        for (int kk = 0; kk < 16; ++kk) {
            int k = q * 16 + kk;
            a += CB[k] * l2w[k * 32 + o];
        }
        zrd[tid] = a;
    }
    __syncthreads();
    if (tid < 32) {
        float v = l2b[tid];
#pragma unroll
        for (int q = 0; q < 8; ++q) v += zrd[q * 32 + tid];
        CB[256 + tid] = fmaxf(v, 0.f);
    }
    __syncthreads();
    if (tid == 0) {
        float o0 = l3b[0], o1 = l3b[1];
        for (int k = 0; k < 32; ++k) {
            float v = CB[256 + k];
            o0 += v * l3w[2 * k];
            o1 += v * l3w[2 * k + 1];
        }
        float m = fmaxf(o0, o1);
        float l = m + logf(expf(o0 - m) + expf(o1 - m));
        out[g * 2 + 0] = o0 - l;
        out[g * 2 + 1] = o1 - l;
    }
}

extern "C" void kernel_launch(void* const* d_in, const int* in_sizes, int n_in,
                              void* d_out, int out_size, void* d_ws, size_t ws_size,
                              hipStream_t stream)
{
    const float* x      = (const float*)d_in[0];
    const int*   ei     = (const int*)d_in[1];
    const float* Wrel1  = (const float*)d_in[2];
    const float* Wroot1 = (const float*)d_in[3];
    const float* b1     = (const float*)d_in[4];
    const float* p1     = (const float*)d_in[5];
    const float* Wrel2  = (const float*)d_in[6];
    const float* Wroot2 = (const float*)d_in[7];
    const float* b2     = (const float*)d_in[8];
    const float* p2     = (const float*)d_in[9];
    const float* l1w    = (const float*)d_in[10];
    const float* l1b    = (const float*)d_in[11];
    const float* l2w    = (const float*)d_in[12];
    const float* l2b    = (const float*)d_in[13];
    const float* l3w    = (const float*)d_in[14];
    const float* l3b    = (const float*)d_in[15];
    float* out = (float*)d_out;

    (void)hipFuncSetAttribute((const void*)fused_gnn,
                              hipFuncAttributeMaxDynamicSharedMemorySize, SMEM_BYTES);

    fused_gnn<<<dim3(NB), dim3(NT), SMEM_BYTES, stream>>>(
        x, ei, Wrel1, Wroot1, b1, p1, Wrel2, Wroot2, b2, p2,
        l1w, l1b, l2w, l2b, l3w, l3b, out);
}

// Round 9
// 875.207 us; speedup vs baseline: 1.2532x; 1.0154x over previous
//
#include <hip/hip_runtime.h>
#include <math.h>

#define NB 1000      // graphs
#define NN 100       // nodes per graph
#define EPG 1000     // edges per graph
#define FIN 14
#define HD 128
#define KP1 80
#define KP2 64
#define NT 512       // threads per block

// LDS float offsets
#define O_HS   0                        // [100][128] = 12800
#define O_CB   12800                    // 3200: conv1 {xg[100][16], ag[100][16]}; conv2 gather [80][32]; readout partials; MLP z1/z2
#define O_SS   16000                    // 1000 ints: CSR sorted sources
#define O_RP   17000                    // 104 ints: rowptr
#define O_SC   17104                    // 100
#define O_MK1  17204                    // 100
#define O_MK2  17304                    // 100 (80 used)
#define O_P1   17404                    // 128
#define O_P2   17532                    // 128
#define O_ZSH  17660                    // 256
#define O_ZRD  17916                    // 512 floats (ints deg[0:128], pos[128:228] during CSR build)
#define O_INV  18428                    // 2
#define O_AL   18430                    // 80 ints: compact alive row list
#define NSM    18510
#define SMEM_BYTES (NSM * 4)            // 74040 B -> 2 blocks/CU (LDS-bound)

// Occupancy model (r5-r8 evidence): occupancy is LDS-bound (74-81KB -> 2
// blocks; >~80KB -> 1 block). VGPR=128 alone still permits 4 waves/SIMD
// (4x128=512=pool). The (NT,4) bound caps VGPR at 64 and ALWAYS spills
// (143MB..2.1GB scratch). Fix: (NT,2) -> cap 128, zero spill, LDS keeps
// 2 blocks/CU = 16 waves.
__global__ __launch_bounds__(NT, 2) void fused_gnn(
    const float* __restrict__ x, const int* __restrict__ ei,
    const float* __restrict__ Wrel1, const float* __restrict__ Wroot1,
    const float* __restrict__ b1, const float* __restrict__ p1,
    const float* __restrict__ Wrel2, const float* __restrict__ Wroot2,
    const float* __restrict__ b2, const float* __restrict__ p2,
    const float* __restrict__ l1w, const float* __restrict__ l1b,
    const float* __restrict__ l2w, const float* __restrict__ l2b,
    const float* __restrict__ l3w, const float* __restrict__ l3b,
    float* __restrict__ out)
{
    extern __shared__ float smf[];
    float* Hs  = smf + O_HS;
    float* CB  = smf + O_CB;
    float* xg  = CB;                 // [100][16] (cols 14,15 zero)
    float* ag  = CB + 1600;          // [100][16]
    int*   ssrc = (int*)(smf + O_SS);
    int*   rowptr = (int*)(smf + O_RP);
    float* sc  = smf + O_SC;
    float* mk1 = smf + O_MK1;
    float* mk2 = smf + O_MK2;
    float* p1s = smf + O_P1;
    float* p2s = smf + O_P2;
    float* zsh = smf + O_ZSH;
    float* zrd = smf + O_ZRD;
    int*   zdi = (int*)(smf + O_ZRD);   // deg[0:128] / pos[128:228] during build
    float* inv = smf + O_INV;
    int*   alive = (int*)(smf + O_AL);  // 80 compact alive rows (ascending)

    const int tid = threadIdx.x;
    const int g = blockIdx.x;
    const int bn = g * NN;
    const int* srcp = ei + g * EPG;
    const int* dstp = ei + NB * EPG + g * EPG;

    // ---------- P0a: stage xg, p vectors + norms, zero deg ----------
    for (int t = tid; t < 1600; t += NT) {
        int i = t >> 4, f = t & 15;
        xg[t] = (f < FIN) ? x[bn * FIN + i * FIN + f] : 0.f;
    }
    if (tid < 128) { p1s[tid] = p1[tid]; p2s[tid] = p2[tid]; zdi[tid] = 0; }
    if (tid >= 256 && tid < 320) {
        int l = tid - 256;
        float a = p1[l], b = p1[l + 64];
        float v = a * a + b * b;
        for (int s = 1; s < 64; s <<= 1) v += __shfl_xor(v, s);
        if (l == 0) inv[0] = rsqrtf(v);
    } else if (tid >= 320 && tid < 384) {
        int l = tid - 320;
        float a = p2[l], b = p2[l + 64];
        float v = a * a + b * b;
        for (int s = 1; s < 64; s <<= 1) v += __shfl_xor(v, s);
        if (l == 0) inv[1] = rsqrtf(v);
    }
    __syncthreads();

    // ---------- P0b: CSR build — count ----------
    for (int e = tid; e < EPG; e += NT) {
        int dl = dstp[e] - bn;
        atomicAdd(&zdi[dl], 1);
    }
    __syncthreads();
    // ---------- P0c: exclusive scan via wave shfl (deg[0:128] -> rowptr) ----------
    if (tid < 64) {
        int a = zdi[tid], b = zdi[tid + 64];
        for (int off = 1; off < 64; off <<= 1) { int t = __shfl_up(a, off); if (tid >= off) a += t; }
        int totA = __shfl(a, 63);
        for (int off = 1; off < 64; off <<= 1) { int t = __shfl_up(b, off); if (tid >= off) b += t; }
        b += totA;
        rowptr[tid + 1] = a;          // inclusive -> rowptr[i+1]
        if (tid + 65 <= 103) rowptr[tid + 65] = b;
        if (tid == 0) rowptr[0] = 0;
    }
    __syncthreads();
    if (tid < NN) zdi[128 + tid] = rowptr[tid];       // pos cursors
    __syncthreads();
    // ---------- P0d: CSR scatter ----------
    for (int e = tid; e < EPG; e += NT) {
        int sl = srcp[e] - bn;
        int dl = dstp[e] - bn;
        int slot = atomicAdd(&zdi[128 + dl], 1);
        ssrc[slot] = sl;
    }
    __syncthreads();

    // ---------- P1: conv1 agg via CSR: ag[i][f] = sum_in-edges xg[src][f] ----------
    {
        const int f = tid & 15;
        if (f < FIN) {
            for (int i = tid >> 4; i < NN; i += 32) {
                int s0 = rowptr[i], s1 = rowptr[i + 1];
                float s = 0.f;
                for (int sl0 = s0; sl0 < s1; ++sl0)
                    s += xg[ssrc[sl0] * 16 + f];
                ag[i * 16 + f] = s;
            }
        }
    }
    __syncthreads();

    // ---------- P2: h1 = relu(ag@Wrel1 + xg@Wroot1 + b1) ----------
    {
        const int j = tid & 127;
        float wr[FIN], wo[FIN];
#pragma unroll
        for (int k = 0; k < FIN; ++k) { wr[k] = Wrel1[k * HD + j]; wo[k] = Wroot1[k * HD + j]; }
        const float bb = b1[j];
        for (int i = tid >> 7; i < NN; i += 4) {
            float s = bb;
#pragma unroll
            for (int k = 0; k < FIN; ++k)
                s += ag[i * 16 + k] * wr[k] + xg[i * 16 + k] * wo[k];
            Hs[i * HD + j] = fmaxf(s, 0.f);
        }
    }
    __syncthreads();

    // ---------- P3: pool1 score + top-80 + compact list + scale + readout1 ----------
    if (tid < 400) {
        const int row = tid >> 2, q = tid & 3;
        float d = 0.f;
        for (int kk = 0; kk < 32; ++kk) {
            int k = q * 32 + ((kk + tid) & 31);
            d += Hs[row * HD + k] * p1s[k];
        }
        d += __shfl_xor(d, 1);
        d += __shfl_xor(d, 2);
        if (q == 0) sc[row] = tanhf(d * inv[0]);
    }
    __syncthreads();
    if (tid < 400) {                    // rank-count, 4 lanes/row
        const int row = tid >> 2, q = tid & 3;
        float si = sc[row]; int cnt = 0;
        for (int j2 = q * 25; j2 < q * 25 + 25; ++j2) cnt += (sc[j2] > si) ? 1 : 0;
        cnt += __shfl_xor(cnt, 1);
        cnt += __shfl_xor(cnt, 2);
        if (q == 0) mk1[row] = (cnt < KP1) ? 1.f : 0.f;
    }
    __syncthreads();
    // compact alive list (wave 0, deterministic ascending) || scale (all threads)
    if (tid < 64) {
        int a = (mk1[tid] > 0.f) ? 1 : 0;
        int b = (tid + 64 < NN && mk1[tid + 64] > 0.f) ? 1 : 0;
        int ia = a, ib = b;
        for (int off = 1; off < 64; off <<= 1) { int t = __shfl_up(ia, off); if (tid >= off) ia += t; }
        int totA = __shfl(ia, 63);
        for (int off = 1; off < 64; off <<= 1) { int t = __shfl_up(ib, off); if (tid >= off) ib += t; }
        int ea = ia - a, eb = totA + ib - b;
        if (a && ea < KP1) alive[ea] = tid;
        if (b && eb < KP1) alive[eb] = tid + 64;
    }
    for (int o = tid; o < NN * HD; o += NT) { int i = o >> 7; Hs[o] *= sc[i] * mk1[i]; }
    __syncthreads();
    {
        const int col = tid & 127, ch = tid >> 7;
        float mean = 0.f, mx = -1e30f;
        for (int i = ch * 25; i < ch * 25 + 25; ++i) {
            float v = Hs[i * HD + col];
            mean += v;
            if (mk1[i] > 0.f && v > mx) mx = v;
        }
        zrd[tid] = mean; CB[tid] = mx;
    }
    __syncthreads();
    if (tid < HD) {
        float mean = zrd[tid] + zrd[128 + tid] + zrd[256 + tid] + zrd[384 + tid];
        float mx = fmaxf(fmaxf(CB[tid], CB[128 + tid]), fmaxf(CB[256 + tid], CB[384 + tid]));
        zsh[tid] = mean * (1.f / KP1);
        zsh[HD + tid] = mx;
    }

    // ---------- P4: conv2 on 80 compact rows: acc = b2 + h1[alive]@Wroot2 + agg@Wrel2 ----------
    const int tr = tid >> 5, tc = tid & 31;     // 16 row-groups x 32 col-groups
    const int i0 = tr * 5, j0 = tc * 4;
    const float4* Wrel2v  = (const float4*)Wrel2;
    const float4* Wroot2v = (const float4*)Wroot2;

    int orow[5];
#pragma unroll
    for (int r = 0; r < 5; ++r) orow[r] = alive[i0 + r];

    float acc[5][4];
    {
        float4 bv = ((const float4*)b2)[tc];
#pragma unroll
        for (int r = 0; r < 5; ++r) { acc[r][0] = bv.x; acc[r][1] = bv.y; acc[r][2] = bv.z; acc[r][3] = bv.w; }
    }
    // root pass: w[4]-batched weight loads, b128 LDS reads (broadcast within 32-lane group)
    for (int k0 = 0; k0 < HD; k0 += 4) {
        float4 w[4];
#pragma unroll
        for (int u = 0; u < 4; ++u) w[u] = Wroot2v[(k0 + u) * 32 + tc];
#pragma unroll
        for (int r = 0; r < 5; ++r) {
            float4 a0 = *(const float4*)&Hs[orow[r] * HD + k0];
            acc[r][0] += a0.x * w[0].x + a0.y * w[1].x + a0.z * w[2].x + a0.w * w[3].x;
            acc[r][1] += a0.x * w[0].y + a0.y * w[1].y + a0.z * w[2].y + a0.w * w[3].y;
            acc[r][2] += a0.x * w[0].z + a0.y * w[1].z + a0.z * w[2].z + a0.w * w[3].z;
            acc[r][3] += a0.x * w[0].w + a0.y * w[1].w + a0.z * w[2].w + a0.w * w[3].w;
        }
    }
    // rel pass: 4 chunks of 32 input cols; CSR gather for alive rows only, then w[4] FMA
    for (int c = 0; c < 4; ++c) {
        __syncthreads();                     // prior CB readers done
        {
            const int jj = tid & 31;
            const int cb = c * 32 + jj;
            for (int r = tid >> 5; r < KP1; r += 16) {
                int i = alive[r];
                int s0 = rowptr[i], s1 = rowptr[i + 1];
                float s = 0.f;
                for (int sl0 = s0; sl0 < s1; ++sl0)
                    s += Hs[ssrc[sl0] * HD + cb];
                CB[r * 32 + jj] = s;
            }
        }
        __syncthreads();
        for (int kk0 = 0; kk0 < 32; kk0 += 4) {
            float4 w[4];
#pragma unroll
            for (int u = 0; u < 4; ++u) w[u] = Wrel2v[(c * 32 + kk0 + u) * 32 + tc];
#pragma unroll
            for (int r = 0; r < 5; ++r) {
                float4 a0 = *(const float4*)&CB[(i0 + r) * 32 + kk0];
                acc[r][0] += a0.x * w[0].x + a0.y * w[1].x + a0.z * w[2].x + a0.w * w[3].x;
                acc[r][1] += a0.x * w[0].y + a0.y * w[1].y + a0.z * w[2].y + a0.w * w[3].y;
                acc[r][2] += a0.x * w[0].z + a0.y * w[1].z + a0.z * w[2].z + a0.w * w[3].z;
                acc[r][3] += a0.x * w[0].w + a0.y * w[1].w + a0.z * w[2].w + a0.w * w[3].w;
            }
        }
    }
    __syncthreads();                          // all gather/root reads of Hs done
    // write h2 compact into Hs rows 0..79 (in place; all reads complete)
#pragma unroll
    for (int r = 0; r < 5; ++r) {
        float4 v;
        v.x = fmaxf(acc[r][0], 0.f); v.y = fmaxf(acc[r][1], 0.f);
        v.z = fmaxf(acc[r][2], 0.f); v.w = fmaxf(acc[r][3], 0.f);
        *(float4*)&Hs[(i0 + r) * HD + j0] = v;
    }
    __syncthreads();

    // ---------- P5: pool2 + readout2 on 80 compact rows ----------
    if (tid < 320) {
        const int row = tid >> 2, q = tid & 3;
        float d = 0.f;
        for (int kk = 0; kk < 32; ++kk) {
            int k = q * 32 + ((kk + tid) & 31);
            d += Hs[row * HD + k] * p2s[k];
        }
        d += __shfl_xor(d, 1);
        d += __shfl_xor(d, 2);
        if (q == 0) sc[row] = tanhf(d * inv[1]);
    }
    __syncthreads();
    if (tid < 320) {                    // rank-count among 80, 4 lanes/row
        const int row = tid >> 2, q = tid & 3;
        float si = sc[row]; int cnt = 0;
        for (int j2 = q * 20; j2 < q * 20 + 20; ++j2) cnt += (sc[j2] > si) ? 1 : 0;
        cnt += __shfl_xor(cnt, 1);
        cnt += __shfl_xor(cnt, 2);
        if (q == 0) mk2[row] = (cnt < KP2) ? 1.f : 0.f;
    }
    __syncthreads();
    for (int o = tid; o < KP1 * HD; o += NT) { int i = o >> 7; Hs[o] *= sc[i] * mk2[i]; }
    __syncthreads();
    {
        const int col = tid & 127, ch = tid >> 7;
        float mean = 0.f, mx = -1e30f;
        for (int i = ch * 20; i < ch * 20 + 20; ++i) {
            float v = Hs[i * HD + col];
            mean += v;
            if (mk2[i] > 0.f && v > mx) mx = v;
        }
        zrd[tid] = mean; CB[tid] = mx;
    }
    __syncthreads();
    if (tid < HD) {
        float mean = zrd[tid] + zrd[128 + tid] + zrd[256 + tid] + zrd[384 + tid];
        float mx = fmaxf(fmaxf(CB[tid], CB[128 + tid]), fmaxf(CB[256 + tid], CB[384 + tid]));
        zsh[tid] += mean * (1.f / KP2);
        zsh[HD + tid] += mx;
    }
    __syncthreads();

    // ---------- P6: MLP + log_softmax (z1 -> CB[0:128], z2 -> CB[256:288]) ----------
    {   // l1: 256 -> 128, k split over 4 chunks of 64
        const int j = tid & 127, q = tid >> 7;
        float a = 0.f;
        for (int kk = 0; kk < 64; ++kk) {
            int k = q * 64 + kk;
            a += zsh[k] * l1w[k * HD + j];
        }
        zrd[tid] = a;
    }
    __syncthreads();
    if (tid < HD)
        CB[tid] = fmaxf(zrd[tid] + zrd[128 + tid] + zrd[256 + tid] + zrd[384 + tid] + l1b[tid], 0.f);
    __syncthreads();
    if (tid < 256) {   // l2: 128 -> 32, k split over 8 chunks of 16
        const int o = tid & 31, q = tid >> 5;
        float a = 0.f;
        for (int kk = 0; kk < 16; ++kk) {
            int k = q * 16 + kk;
            a += CB[k] * l2w[k * 32 + o];
        }
        zrd[tid] = a;
    }
    __syncthreads();
    if (tid < 32) {
        float v = l2b[tid];
#pragma unroll
        for (int q = 0; q < 8; ++q) v += zrd[q * 32 + tid];
        CB[256 + tid] = fmaxf(v, 0.f);
    }
    __syncthreads();
    if (tid == 0) {
        float o0 = l3b[0], o1 = l3b[1];
        for (int k = 0; k < 32; ++k) {
            float v = CB[256 + k];
            o0 += v * l3w[2 * k];
            o1 += v * l3w[2 * k + 1];
        }
        float m = fmaxf(o0, o1);
        float l = m + logf(expf(o0 - m) + expf(o1 - m));
        out[g * 2 + 0] = o0 - l;
        out[g * 2 + 1] = o1 - l;
    }
}

extern "C" void kernel_launch(void* const* d_in, const int* in_sizes, int n_in,
                              void* d_out, int out_size, void* d_ws, size_t ws_size,
                              hipStream_t stream)
{
    const float* x      = (const float*)d_in[0];
    const int*   ei     = (const int*)d_in[1];
    const float* Wrel1  = (const float*)d_in[2];
    const float* Wroot1 = (const float*)d_in[3];
    const float* b1     = (const float*)d_in[4];
    const float* p1     = (const float*)d_in[5];
    const float* Wrel2  = (const float*)d_in[6];
    const float* Wroot2 = (const float*)d_in[7];
    const float* b2     = (const float*)d_in[8];
    const float* p2     = (const float*)d_in[9];
    const float* l1w    = (const float*)d_in[10];
    const float* l1b    = (const float*)d_in[11];
    const float* l2w    = (const float*)d_in[12];
    const float* l2b    = (const float*)d_in[13];
    const float* l3w    = (const float*)d_in[14];
    const float* l3b    = (const float*)d_in[15];
    float* out = (float*)d_out;

    (void)hipFuncSetAttribute((const void*)fused_gnn,
                              hipFuncAttributeMaxDynamicSharedMemorySize, SMEM_BYTES);

    fused_gnn<<<dim3(NB), dim3(NT), SMEM_BYTES, stream>>>(
        x, ei, Wrel1, Wroot1, b1, p1, Wrel2, Wroot2, b2, p2,
        l1w, l1b, l2w, l2b, l3w, l3b, out);
}

// Round 10
// 300.964 us; speedup vs baseline: 3.6444x; 2.9080x over previous
//
#include <hip/hip_runtime.h>
#include <math.h>

#define NB 1000      // graphs
#define NN 100       // nodes per graph
#define EPG 1000     // edges per graph
#define FIN 14
#define HD 128
#define KP1 80
#define KP2 64
#define NT 512       // threads per block

// LDS float offsets (NO pad rows: 72 KB total -> 2 blocks/CU)
#define O_HS   0                        // [100][128] = 12800
#define O_CB   12800                    // [100][32] = 3200 (alias xg[0:1600], ag[1600:3200])
#define O_SS   16000                    // 1000 ints: CSR sorted sources
#define O_RP   17000                    // 104 ints: rowptr
#define O_SC   17104                    // 100
#define O_MK1  17204                    // 100
#define O_MK2  17304                    // 100
#define O_P1   17404                    // 128
#define O_P2   17532                    // 128
#define O_ZSH  17660                    // 256
#define O_ZRD  17916                    // 512 floats (ints deg[0:128], pos[128:228] during CSR build)
#define O_INV  18428                    // 2
#define NSM    18430
#define SMEM_BYTES (NSM * 4)            // 73720 B = 72 KB -> 2 blocks/CU

// Cross-round model (r5-r9):
//  - 2nd launch_bounds arg acts as blocks/CU: (512,4)->VGPR cap 64 (always
//    spilled 143MB..2.1GB), (512,2)->cap 128.
//  - r6 (this exact P4 structure, cap 128): VGPR=120, ZERO spill. Its only
//    problem: LDS 81.4KB > 80KB -> 1 block/CU (22.7% occ).
//  - r8/r9's alive[]-compacted P4 spilled ~1.5GB even at cap 128 -> avoided.
// Fix here: r6 structure + LDS 72KB (no pad rows; clamped reads, guarded
// stores) -> 2 blocks/CU, 16 waves, no spill.
__global__ __launch_bounds__(NT, 2) void fused_gnn(
    const float* __restrict__ x, const int* __restrict__ ei,
    const float* __restrict__ Wrel1, const float* __restrict__ Wroot1,
    const float* __restrict__ b1, const float* __restrict__ p1,
    const float* __restrict__ Wrel2, const float* __restrict__ Wroot2,
    const float* __restrict__ b2, const float* __restrict__ p2,
    const float* __restrict__ l1w, const float* __restrict__ l1b,
    const float* __restrict__ l2w, const float* __restrict__ l2b,
    const float* __restrict__ l3w, const float* __restrict__ l3b,
    float* __restrict__ out)
{
    extern __shared__ float smf[];
    float* Hs  = smf + O_HS;
    float* CB  = smf + O_CB;
    float* xg  = CB;                 // [100][16] (cols 14,15 zero)
    float* ag  = CB + 1600;          // [100][16]
    int*   ssrc = (int*)(smf + O_SS);
    int*   rowptr = (int*)(smf + O_RP);
    float* sc  = smf + O_SC;
    float* mk1 = smf + O_MK1;
    float* mk2 = smf + O_MK2;
    float* p1s = smf + O_P1;
    float* p2s = smf + O_P2;
    float* zsh = smf + O_ZSH;
    float* zrd = smf + O_ZRD;
    int*   zdi = (int*)(smf + O_ZRD);   // deg[0:128] / pos[128:228] during build
    float* inv = smf + O_INV;

    const int tid = threadIdx.x;
    const int g = blockIdx.x;
    const int bn = g * NN;
    const int* srcp = ei + g * EPG;
    const int* dstp = ei + NB * EPG + g * EPG;

    // ---------- P0a: stage xg, zero ag, p vectors + norms, zero deg ----------
    for (int t = tid; t < 1600; t += NT) {
        int i = t >> 4, f = t & 15;
        xg[t] = (f < FIN) ? x[bn * FIN + i * FIN + f] : 0.f;
        ag[t] = 0.f;
    }
    if (tid < 128) { p1s[tid] = p1[tid]; p2s[tid] = p2[tid]; zdi[tid] = 0; }
    if (tid >= 256 && tid < 320) {
        int l = tid - 256;
        float a = p1[l], b = p1[l + 64];
        float v = a * a + b * b;
        for (int s = 1; s < 64; s <<= 1) v += __shfl_xor(v, s);
        if (l == 0) inv[0] = rsqrtf(v);
    } else if (tid >= 320 && tid < 384) {
        int l = tid - 320;
        float a = p2[l], b = p2[l + 64];
        float v = a * a + b * b;
        for (int s = 1; s < 64; s <<= 1) v += __shfl_xor(v, s);
        if (l == 0) inv[1] = rsqrtf(v);
    }
    __syncthreads();

    // ---------- P0b: CSR build — count ----------
    for (int e = tid; e < EPG; e += NT) {
        int dl = dstp[e] - bn;
        atomicAdd(&zdi[dl], 1);
    }
    __syncthreads();
    // ---------- P0c: exclusive scan via wave shfl (deg[0:128] -> rowptr) ----------
    if (tid < 64) {
        int a = zdi[tid], b = zdi[tid + 64];
        for (int off = 1; off < 64; off <<= 1) { int t = __shfl_up(a, off); if (tid >= off) a += t; }
        int totA = __shfl(a, 63);
        for (int off = 1; off < 64; off <<= 1) { int t = __shfl_up(b, off); if (tid >= off) b += t; }
        b += totA;
        rowptr[tid + 1] = a;          // inclusive -> rowptr[i+1]
        if (tid + 65 <= 103) rowptr[tid + 65] = b;
        if (tid == 0) rowptr[0] = 0;
    }
    __syncthreads();
    if (tid < NN) zdi[128 + tid] = rowptr[tid];       // pos cursors
    __syncthreads();
    // ---------- P0d: CSR scatter ----------
    for (int e = tid; e < EPG; e += NT) {
        int sl = srcp[e] - bn;
        int dl = dstp[e] - bn;
        int slot = atomicAdd(&zdi[128 + dl], 1);
        ssrc[slot] = sl;
    }
    __syncthreads();

    // ---------- P1: conv1 agg via CSR: ag[i][f] = sum_in-edges xg[src][f] ----------
    {
        const int f = tid & 15;
        if (f < FIN) {
            for (int i = tid >> 4; i < NN; i += 32) {
                int s0 = rowptr[i], s1 = rowptr[i + 1];
                float s = 0.f;
                for (int sl0 = s0; sl0 < s1; ++sl0)
                    s += xg[ssrc[sl0] * 16 + f];
                ag[i * 16 + f] = s;
            }
        }
    }
    __syncthreads();

    // ---------- P2: h1 = relu(ag@Wrel1 + xg@Wroot1 + b1) ----------
    {
        const int j = tid & 127;
        float wr[FIN], wo[FIN];
#pragma unroll
        for (int k = 0; k < FIN; ++k) { wr[k] = Wrel1[k * HD + j]; wo[k] = Wroot1[k * HD + j]; }
        const float bb = b1[j];
        for (int i = tid >> 7; i < NN; i += 4) {
            float s = bb;
#pragma unroll
            for (int k = 0; k < FIN; ++k)
                s += ag[i * 16 + k] * wr[k] + xg[i * 16 + k] * wo[k];
            Hs[i * HD + j] = fmaxf(s, 0.f);
        }
    }
    __syncthreads();

    // ---------- P3: pool1 score + top-80 + scale + readout1 ----------
    if (tid < 400) {
        const int row = tid >> 2, q = tid & 3;
        float d = 0.f;
        for (int kk = 0; kk < 32; ++kk) {
            int k = q * 32 + ((kk + tid) & 31);
            d += Hs[row * HD + k] * p1s[k];
        }
        d += __shfl_xor(d, 1);
        d += __shfl_xor(d, 2);
        if (q == 0) sc[row] = tanhf(d * inv[0]);
    }
    __syncthreads();
    if (tid < 400) {                    // rank-count, 4 lanes/row
        const int row = tid >> 2, q = tid & 3;
        float si = sc[row]; int cnt = 0;
        for (int j2 = q * 25; j2 < q * 25 + 25; ++j2) cnt += (sc[j2] > si) ? 1 : 0;
        cnt += __shfl_xor(cnt, 1);
        cnt += __shfl_xor(cnt, 2);
        if (q == 0) mk1[row] = (cnt < KP1) ? 1.f : 0.f;
    }
    __syncthreads();
    for (int o = tid; o < NN * HD; o += NT) { int i = o >> 7; Hs[o] *= sc[i] * mk1[i]; }
    __syncthreads();
    {
        const int col = tid & 127, ch = tid >> 7;
        float mean = 0.f, mx = -1e30f;
        for (int i = ch * 25; i < ch * 25 + 25; ++i) {
            float v = Hs[i * HD + col];
            mean += v;
            if (mk1[i] > 0.f && v > mx) mx = v;
        }
        zrd[tid] = mean; CB[tid] = mx;
    }
    __syncthreads();
    if (tid < HD) {
        float mean = zrd[tid] + zrd[128 + tid] + zrd[256 + tid] + zrd[384 + tid];
        float mx = fmaxf(fmaxf(CB[tid], CB[128 + tid]), fmaxf(CB[256 + tid], CB[384 + tid]));
        zsh[tid] = mean * (1.f / KP1);
        zsh[HD + tid] = mx;
    }

    // ---------- P4: conv2: acc = b2 + Hs@Wroot2 + sum_c CSRagg@Wrel2 ----------
    const int tr = tid >> 5, tc = tid & 31;     // 16 row-groups x 32 col-groups
    const int i0 = tr * 7, j0 = tc * 4;
    const float4* Wrel2v  = (const float4*)Wrel2;
    const float4* Wroot2v = (const float4*)Wroot2;

    int rowc[7];                                 // clamped read rows (stores guarded)
#pragma unroll
    for (int r = 0; r < 7; ++r) rowc[r] = (i0 + r < NN) ? (i0 + r) : (NN - 1);

    float acc[7][4];
    {
        float4 bv = ((const float4*)b2)[tc];
#pragma unroll
        for (int r = 0; r < 7; ++r) { acc[r][0] = bv.x; acc[r][1] = bv.y; acc[r][2] = bv.z; acc[r][3] = bv.w; }
    }
    // root pass: unroll-8 batched weight loads, b128 LDS reads (r6 codegen)
    for (int k0 = 0; k0 < HD; k0 += 8) {
        float4 w[8];
#pragma unroll
        for (int u = 0; u < 8; ++u) w[u] = Wroot2v[(k0 + u) * 32 + tc];
#pragma unroll
        for (int r = 0; r < 7; ++r) {
            float4 a0 = *(const float4*)&Hs[rowc[r] * HD + k0];
            float4 a1 = *(const float4*)&Hs[rowc[r] * HD + k0 + 4];
            acc[r][0] += a0.x * w[0].x + a0.y * w[1].x + a0.z * w[2].x + a0.w * w[3].x
                       + a1.x * w[4].x + a1.y * w[5].x + a1.z * w[6].x + a1.w * w[7].x;
            acc[r][1] += a0.x * w[0].y + a0.y * w[1].y + a0.z * w[2].y + a0.w * w[3].y
                       + a1.x * w[4].y + a1.y * w[5].y + a1.z * w[6].y + a1.w * w[7].y;
            acc[r][2] += a0.x * w[0].z + a0.y * w[1].z + a0.z * w[2].z + a0.w * w[3].z
                       + a1.x * w[4].z + a1.y * w[5].z + a1.z * w[6].z + a1.w * w[7].z;
            acc[r][3] += a0.x * w[0].w + a0.y * w[1].w + a0.z * w[2].w + a0.w * w[3].w
                       + a1.x * w[4].w + a1.y * w[5].w + a1.z * w[6].w + a1.w * w[7].w;
        }
    }
    // rel pass: 4 chunks of 32 cols; CSR gather (no atomics) then unroll-8 FMA
    for (int c = 0; c < 4; ++c) {
        __syncthreads();                     // prior CB readers done
        {
            const int jj = tid & 31;
            const int cb = c * 32 + jj;
            for (int i = tid >> 5; i < NN; i += 16) {
                int s0 = rowptr[i], s1 = rowptr[i + 1];
                float s = 0.f;
                for (int sl0 = s0; sl0 < s1; ++sl0)
                    s += Hs[ssrc[sl0] * HD + cb];
                CB[i * 32 + jj] = s;
            }
        }
        __syncthreads();
        for (int kk0 = 0; kk0 < 32; kk0 += 8) {
            float4 w[8];
#pragma unroll
            for (int u = 0; u < 8; ++u) w[u] = Wrel2v[(c * 32 + kk0 + u) * 32 + tc];
#pragma unroll
            for (int r = 0; r < 7; ++r) {
                float4 a0 = *(const float4*)&CB[rowc[r] * 32 + kk0];
                float4 a1 = *(const float4*)&CB[rowc[r] * 32 + kk0 + 4];
                acc[r][0] += a0.x * w[0].x + a0.y * w[1].x + a0.z * w[2].x + a0.w * w[3].x
                           + a1.x * w[4].x + a1.y * w[5].x + a1.z * w[6].x + a1.w * w[7].x;
                acc[r][1] += a0.x * w[0].y + a0.y * w[1].y + a0.z * w[2].y + a0.w * w[3].y
                           + a1.x * w[4].y + a1.y * w[5].y + a1.z * w[6].y + a1.w * w[7].y;
                acc[r][2] += a0.x * w[0].z + a0.y * w[1].z + a0.z * w[2].z + a0.w * w[3].z
                           + a1.x * w[4].z + a1.y * w[5].z + a1.z * w[6].z + a1.w * w[7].z;
                acc[r][3] += a0.x * w[0].w + a0.y * w[1].w + a0.z * w[2].w + a0.w * w[3].w
                           + a1.x * w[4].w + a1.y * w[5].w + a1.z * w[6].w + a1.w * w[7].w;
            }
        }
    }
    __syncthreads();                          // all readers of Hs done
    // write h2 = relu(acc) into Hs, guarded (no pad rows)
#pragma unroll
    for (int r = 0; r < 7; ++r) {
        if (i0 + r < NN) {
            float4 v;
            v.x = fmaxf(acc[r][0], 0.f); v.y = fmaxf(acc[r][1], 0.f);
            v.z = fmaxf(acc[r][2], 0.f); v.w = fmaxf(acc[r][3], 0.f);
            *(float4*)&Hs[(i0 + r) * HD + j0] = v;
        }
    }
    __syncthreads();

    // ---------- P5: pool2 + readout2 ----------
    if (tid < 400) {
        const int row = tid >> 2, q = tid & 3;
        float d = 0.f;
        for (int kk = 0; kk < 32; ++kk) {
            int k = q * 32 + ((kk + tid) & 31);
            d += Hs[row * HD + k] * p2s[k];
        }
        d += __shfl_xor(d, 1);
        d += __shfl_xor(d, 2);
        if (q == 0) sc[row] = (mk1[row] > 0.f) ? tanhf(d * inv[1]) : -1e30f;
    }
    __syncthreads();
    if (tid < 400) {                    // rank-count, 4 lanes/row
        const int row = tid >> 2, q = tid & 3;
        float si = sc[row]; int cnt = 0;
        for (int j2 = q * 25; j2 < q * 25 + 25; ++j2) cnt += (sc[j2] > si) ? 1 : 0;
        cnt += __shfl_xor(cnt, 1);
        cnt += __shfl_xor(cnt, 2);
        if (q == 0) mk2[row] = (mk1[row] > 0.f && cnt < KP2) ? 1.f : 0.f;
    }
    __syncthreads();
    for (int o = tid; o < NN * HD; o += NT) { int i = o >> 7; Hs[o] *= sc[i] * mk2[i]; }
    __syncthreads();
    {
        const int col = tid & 127, ch = tid >> 7;
        float mean = 0.f, mx = -1e30f;
        for (int i = ch * 25; i < ch * 25 + 25; ++i) {
            float v = Hs[i * HD + col];
            mean += v;
            if (mk2[i] > 0.f && v > mx) mx = v;
        }
        zrd[tid] = mean; CB[tid] = mx;
    }
    __syncthreads();
    if (tid < HD) {
        float mean = zrd[tid] + zrd[128 + tid] + zrd[256 + tid] + zrd[384 + tid];
        float mx = fmaxf(fmaxf(CB[tid], CB[128 + tid]), fmaxf(CB[256 + tid], CB[384 + tid]));
        zsh[tid] += mean * (1.f / KP2);
        zsh[HD + tid] += mx;
    }
    __syncthreads();

    // ---------- P6: MLP + log_softmax (z1 -> CB[0:128], z2 -> CB[256:288]) ----------
    {   // l1: 256 -> 128, k split over 4 chunks of 64
        const int j = tid & 127, q = tid >> 7;
        float a = 0.f;
        for (int kk = 0; kk < 64; ++kk) {
            int k = q * 64 + kk;
            a += zsh[k] * l1w[k * HD + j];
        }
        zrd[tid] = a;
    }
    __syncthreads();
    if (tid < HD)
        CB[tid] = fmaxf(zrd[tid] + zrd[128 + tid] + zrd[256 + tid] + zrd[384 + tid] + l1b[tid], 0.f);
    __syncthreads();
    if (tid < 256) {   // l2: 128 -> 32, k split over 8 chunks of 16
        const int o = tid & 31, q = tid >> 5;
        float a = 0.f;
        for (int kk = 0; kk < 16; ++kk) {
            int k = q * 16 + kk;
            a += CB[k] * l2w[k * 32 + o];
        }
        zrd[tid] = a;
    }
    __syncthreads();
    if (tid < 32) {
        float v = l2b[tid];
#pragma unroll
        for (int q = 0; q < 8; ++q) v += zrd[q * 32 + tid];
        CB[256 + tid] = fmaxf(v, 0.f);
    }
    __syncthreads();
    if (tid == 0) {
        float o0 = l3b[0], o1 = l3b[1];
        for (int k = 0; k < 32; ++k) {
            float v = CB[256 + k];
            o0 += v * l3w[2 * k];
            o1 += v * l3w[2 * k + 1];
        }
        float m = fmaxf(o0, o1);
        float l = m + logf(expf(o0 - m) + expf(o1 - m));
        out[g * 2 + 0] = o0 - l;
        out[g * 2 + 1] = o1 - l;
    }
}

extern "C" void kernel_launch(void* const* d_in, const int* in_sizes, int n_in,
                              void* d_out, int out_size, void* d_ws, size_t ws_size,
                              hipStream_t stream)
{
    const float* x      = (const float*)d_in[0];
    const int*   ei     = (const int*)d_in[1];
    const float* Wrel1  = (const float*)d_in[2];
    const float* Wroot1 = (const float*)d_in[3];
    const float* b1     = (const float*)d_in[4];
    const float* p1     = (const float*)d_in[5];
    const float* Wrel2  = (const float*)d_in[6];
    const float* Wroot2 = (const float*)d_in[7];
    const float* b2     = (const float*)d_in[8];
    const float* p2     = (const float*)d_in[9];
    const float* l1w    = (const float*)d_in[10];
    const float* l1b    = (const float*)d_in[11];
    const float* l2w    = (const float*)d_in[12];
    const float* l2b    = (const float*)d_in[13];
    const float* l3w    = (const float*)d_in[14];
    const float* l3b    = (const float*)d_in[15];
    float* out = (float*)d_out;

    (void)hipFuncSetAttribute((const void*)fused_gnn,
                              hipFuncAttributeMaxDynamicSharedMemorySize, SMEM_BYTES);

    fused_gnn<<<dim3(NB), dim3(NT), SMEM_BYTES, stream>>>(
        x, ei, Wrel1, Wroot1, b1, p1, Wrel2, Wroot2, b2, p2,
        l1w, l1b, l2w, l2b, l3w, l3b, out);
}